// Round 6
// baseline (288.462 us; speedup 1.0000x reference)
//
#include <hip/hip_runtime.h>
#include <stdint.h>

typedef unsigned int u32;
typedef unsigned char u8;
typedef unsigned long long u64;

#define NB 256
#define NC 20
#define BLK 256
#define NCTR (NC * NB)
#define DUMP_BYTES (NCTR * 4)
#define FINAL_U32 (NCTR * 2)
#define OFF_CE   (FINAL_U32 * 4)
#define OFF_CNT  (OFF_CE + 4)
#define OFF_DUMPS 65536
#define RESERVED  OFF_DUMPS
#define NBLK 1024

#define KEEPF(x) asm volatile("" :: "v"(x))
#define KEEPU(x) asm volatile("" :: "v"(x))

// ---------------- float4 helpers ----------------
__device__ __forceinline__ float4 f4max(float4 a, float4 b) {
    return make_float4(fmaxf(a.x,b.x), fmaxf(a.y,b.y), fmaxf(a.z,b.z), fmaxf(a.w,b.w));
}
__device__ __forceinline__ float4 f4add(float4 a, float4 b) {
    return make_float4(a.x+b.x, a.y+b.y, a.z+b.z, a.w+b.w);
}
__device__ __forceinline__ float4 f4expsub(float4 a, float m) {
    return make_float4(__expf(a.x-m), __expf(a.y-m), __expf(a.z-m), __expf(a.w-m));
}
__device__ __forceinline__ u32 bin1(float e, float inv, int c, int t, float& pt) {
    float p = e * inv;
    if (c == t) pt = p;
    float err = (c == t) ? 1.0f - p : p;
    int b = (int)(err * 256.0f);
    return (u32)(b > 255 ? 255 : b);
}
__device__ __forceinline__ u32 pack4(float4 e, float inv, int cb, int t, float& pt) {
    return  bin1(e.x, inv, cb+0, t, pt)
         | (bin1(e.y, inv, cb+1, t, pt) << 8)
         | (bin1(e.z, inv, cb+2, t, pt) << 16)
         | (bin1(e.w, inv, cb+3, t, pt) << 24);
}

// ---------------- ablation probes (no stores; DCE-protected) ----------------
// LVL 0: loads only.  LVL 1: + softmax (max/exp/sum/rcp).  LVL 2: + bin-pack + log.
template<int LVL>
__global__ __launch_bounds__(BLK) void probe(
    const float* __restrict__ logits, const int* __restrict__ tgt, int P)
{
    int tid = blockIdx.x * BLK + threadIdx.x;
    int stride = gridDim.x * BLK;
    float accf = 0.f;
    u32   accu = 0;

    for (int idx = tid; idx < P; idx += stride) {
        const float4* row = (const float4*)(logits + (size_t)idx * NC);
        float4 v0 = row[0], v1 = row[1], v2 = row[2], v3 = row[3], v4 = row[4];
        int t = tgt[idx];

        if constexpr (LVL == 0) {
            float4 s4 = f4add(f4add(v0, v1), f4add(v2, v3));
            s4 = f4add(s4, v4);
            accf += (s4.x + s4.y) + (s4.z + s4.w) + (float)t;
        } else {
            float4 m4 = f4max(f4max(v0, v1), f4max(v2, v3));
            m4 = f4max(m4, v4);
            float mx = fmaxf(fmaxf(m4.x, m4.y), fmaxf(m4.z, m4.w));
            float4 e0 = f4expsub(v0, mx);
            float4 e1 = f4expsub(v1, mx);
            float4 e2 = f4expsub(v2, mx);
            float4 e3 = f4expsub(v3, mx);
            float4 e4 = f4expsub(v4, mx);
            float4 s4 = f4add(f4add(e0, e1), f4add(e2, e3));
            s4 = f4add(s4, e4);
            float s = (s4.x + s4.y) + (s4.z + s4.w);
            float inv = 1.0f / s;
            if constexpr (LVL == 1) {
                accf += inv;
            } else {
                float pt = 1.0f;
                u32 w0 = pack4(e0, inv, 0,  t, pt);
                u32 w1 = pack4(e1, inv, 4,  t, pt);
                u32 w2 = pack4(e2, inv, 8,  t, pt);
                u32 w3 = pack4(e3, inv, 12, t, pt);
                u32 w4 = pack4(e4, inv, 16, t, pt);
                accu ^= (w0 ^ w1) ^ (w2 ^ w3) ^ w4;
                if (t != 0) accf -= __logf(pt);
            }
        }
        KEEPF(accf);
        KEEPU(accu);
    }
}

// ---------------- k1a: streaming softmax + CE + bin-pack (R4 structure) ----------------
__global__ __launch_bounds__(BLK) void k1a_bins(
    const float* __restrict__ logits, const int* __restrict__ tgt, int P,
    u32* __restrict__ bins, u8* __restrict__ t8,
    float* __restrict__ ce_sum, u32* __restrict__ valid_cnt)
{
    int tid = blockIdx.x * BLK + threadIdx.x;
    int stride = gridDim.x * BLK;
    float ce_part = 0.f;
    u32   cnt_part = 0;

    for (int idx = tid; idx < P; idx += stride) {
        const float4* row = (const float4*)(logits + (size_t)idx * NC);
        float4 v0 = row[0], v1 = row[1], v2 = row[2], v3 = row[3], v4 = row[4];
        int t = tgt[idx];

        float4 m4 = f4max(f4max(v0, v1), f4max(v2, v3));
        m4 = f4max(m4, v4);
        float mx = fmaxf(fmaxf(m4.x, m4.y), fmaxf(m4.z, m4.w));

        float4 e0 = f4expsub(v0, mx);
        float4 e1 = f4expsub(v1, mx);
        float4 e2 = f4expsub(v2, mx);
        float4 e3 = f4expsub(v3, mx);
        float4 e4 = f4expsub(v4, mx);

        float4 s4 = f4add(f4add(e0, e1), f4add(e2, e3));
        s4 = f4add(s4, e4);
        float s = (s4.x + s4.y) + (s4.z + s4.w);
        float inv = 1.0f / s;

        float pt = 1.0f;
        u32 w0 = pack4(e0, inv, 0,  t, pt);
        u32 w1 = pack4(e1, inv, 4,  t, pt);
        u32 w2 = pack4(e2, inv, 8,  t, pt);
        u32 w3 = pack4(e3, inv, 12, t, pt);
        u32 w4 = pack4(e4, inv, 16, t, pt);

        bins[idx]                 = w0;
        bins[(size_t)P + idx]     = w1;
        bins[(size_t)2 * P + idx] = w2;
        bins[(size_t)3 * P + idx] = w3;
        bins[(size_t)4 * P + idx] = w4;
        t8[idx] = (u8)t;

        if (t != 0) { ce_part -= __logf(pt); cnt_part++; }
    }

    #pragma unroll
    for (int off = 32; off > 0; off >>= 1) {
        ce_part  += __shfl_down(ce_part, off);
        cnt_part += __shfl_down(cnt_part, off);
    }
    if ((threadIdx.x & 63) == 0) {
        atomicAdd(ce_sum, ce_part);
        atomicAdd(valid_cnt, cnt_part);
    }
}

// ---------------- k1b: histogram from packed bins ----------------
__global__ void k1b_hist(
    const u32* __restrict__ bins, const u8* __restrict__ t8, int P,
    u32* __restrict__ dumps)
{
    __shared__ u32 h[NCTR];
    for (int i = threadIdx.x; i < NCTR; i += BLK) h[i] = 0;
    __syncthreads();

    int tid = blockIdx.x * BLK + threadIdx.x;
    for (int idx = tid; idx < P; idx += NBLK * BLK) {
        u32 w0 = bins[idx];
        u32 w1 = bins[(size_t)P + idx];
        u32 w2 = bins[(size_t)2 * P + idx];
        u32 w3 = bins[(size_t)3 * P + idx];
        u32 w4 = bins[(size_t)4 * P + idx];
        int t = t8[idx];
        u32 w[5] = { w0, w1, w2, w3, w4 };
        #pragma unroll
        for (int j = 0; j < 5; ++j) {
            #pragma unroll
            for (int k = 0; k < 4; ++k) {
                int c = j * 4 + k;
                u32 b = (w[j] >> (8 * k)) & 255u;
                atomicAdd(&h[(u32)c * 256u + b], (c == t) ? 0x10001u : 1u);
            }
        }
    }

    __syncthreads();
    u32* d = dumps + (size_t)blockIdx.x * NCTR;
    for (int i = threadIdx.x; i < NCTR; i += BLK) d[i] = h[i];
}

// ---------------- k2a: reduce + unpack per-block dumps ----------------
__global__ __launch_bounds__(256) void k2a_reduce(
    const u32* __restrict__ dumps, u32* __restrict__ final_hist, int nblk, int chunk)
{
    int counter = (blockIdx.x % 20) * 256 + threadIdx.x;
    int part    = blockIdx.x / 20;
    int b0 = part * chunk;
    int b1 = b0 + chunk; if (b1 > nblk) b1 = nblk;
    u32 lo = 0, hi = 0;
    for (int blk = b0; blk < b1; ++blk) {
        u32 v = dumps[(size_t)blk * NCTR + counter];
        lo += v & 0xFFFFu;
        hi += v >> 16;
    }
    if (lo) atomicAdd(&final_hist[counter], lo);
    if (hi) atomicAdd(&final_hist[NCTR + counter], hi);
}

// ---------------- k2b: per-class descending bin scan + finalize ----------------
__device__ __forceinline__ float jac_of(float gts, u32 cf, u32 ct)
{
    float I = gts - (float)cf;
    float U = gts + (float)ct - (float)cf;
    return 1.0f - I / U;
}

__global__ __launch_bounds__(256) void k2b_final(
    const u32* __restrict__ final_hist, const float* __restrict__ ce_sum,
    const u32* __restrict__ valid_cnt, float* __restrict__ outp)
{
    __shared__ u64 sc[NB];
    __shared__ float red[NB];
    int t = threadIdx.x;

    float lovsum = 0.f;
    int prescnt = 0;

    for (int c = 0; c < NC; ++c) {
        int b = NB - 1 - t;
        u32 tot = final_hist[c * NB + b];
        u32 fg  = final_hist[NCTR + c * NB + b];
        u64 v = ((u64)fg << 32) | (u64)tot;

        sc[t] = v;
        __syncthreads();
        for (int off = 1; off < NB; off <<= 1) {
            u64 add = (t >= off) ? sc[t - off] : 0ull;
            __syncthreads();
            sc[t] += add;
            __syncthreads();
        }
        u64 incl  = sc[t];
        u64 total = sc[NB - 1];
        float gts = (float)(u32)(total >> 32);

        float contrib = 0.f;
        if (gts > 0.f) {
            u64 excl = incl - v;
            float jE = jac_of(gts, (u32)(excl >> 32), (u32)excl);
            float jI = jac_of(gts, (u32)(incl >> 32), (u32)incl);
            float eb = ((float)b + 0.5f) * (1.0f / (float)NB);
            contrib = eb * (jI - jE);
        }

        red[t] = contrib;
        __syncthreads();
        #pragma unroll
        for (int off = NB / 2; off > 0; off >>= 1) {
            if (t < off) red[t] += red[t + off];
            __syncthreads();
        }
        if (t == 0 && gts > 0.f) { lovsum += red[0]; prescnt++; }
        __syncthreads();
    }

    if (t == 0) {
        u32 vc = *valid_cnt; if (vc < 1u) vc = 1u;
        float ce = *ce_sum / (float)vc;
        int pc = prescnt < 1 ? 1 : prescnt;
        float lov = lovsum / (float)pc;
        outp[0] = 2.0f * ce;
        outp[1] = 6.0f * lov;
    }
}

// ---------------- launch ----------------
extern "C" void kernel_launch(void* const* d_in, const int* in_sizes, int n_in,
                              void* d_out, int out_size, void* d_ws, size_t ws_size,
                              hipStream_t stream)
{
    const float* logits = (const float*)d_in[0];
    const int*   tgt    = (const int*)d_in[1];
    int P = in_sizes[1];

    char* ws = (char*)d_ws;
    u32*  final_hist = (u32*)ws;
    float* ce_sum    = (float*)(ws + OFF_CE);
    u32*  valid_cnt  = (u32*)(ws + OFF_CNT);
    u32*  dumps      = (u32*)(ws + OFF_DUMPS);

    size_t off_bins = (size_t)OFF_DUMPS + (size_t)NBLK * DUMP_BYTES;
    u32* bins = (u32*)(ws + off_bins);
    u8*  t8   = (u8*)(ws + off_bins + (size_t)5 * P * 4);

    // ---- ablation probes (read-only; rocprof attributes each dispatch) ----
    hipLaunchKernelGGL((probe<0>), dim3(NBLK), dim3(BLK), 0, stream, logits, tgt, P); // pA: loads, 1024 blk
    hipLaunchKernelGGL((probe<0>), dim3(256),  dim3(BLK), 0, stream, logits, tgt, P); // pA2: loads, 256 blk
    hipLaunchKernelGGL((probe<1>), dim3(NBLK), dim3(BLK), 0, stream, logits, tgt, P); // pB: +softmax
    hipLaunchKernelGGL((probe<2>), dim3(NBLK), dim3(BLK), 0, stream, logits, tgt, P); // pC: +bins (full compute)

    // ---- real pipeline ----
    hipMemsetAsync(d_ws, 0, RESERVED, stream);
    hipLaunchKernelGGL(k1a_bins, dim3(NBLK), dim3(BLK), 0, stream,
                       logits, tgt, P, bins, t8, ce_sum, valid_cnt);
    hipLaunchKernelGGL(k1b_hist, dim3(NBLK), dim3(BLK), 0, stream,
                       bins, t8, P, dumps);
    int split = 32;
    int chunk = (NBLK + split - 1) / split;
    hipLaunchKernelGGL(k2a_reduce, dim3(20 * split), dim3(256), 0, stream,
                       dumps, final_hist, NBLK, chunk);
    hipLaunchKernelGGL(k2b_final, dim3(1), dim3(NB), 0, stream,
                       final_hist, ce_sum, valid_cnt, (float*)d_out);
}

// Round 8
// 255.346 us; speedup vs baseline: 1.1297x; 1.1297x over previous
//
#include <hip/hip_runtime.h>
#include <stdint.h>

typedef unsigned int u32;
typedef unsigned char u8;
typedef unsigned long long u64;
typedef int v4i __attribute__((ext_vector_type(4)));

#define NB 256
#define NC 20
#define BLK 256
#define NCTR (NC * NB)
#define DUMP_BYTES (NCTR * 4)
#define FINAL_U32 (NCTR * 2)
#define OFF_CE   (FINAL_U32 * 4)
#define OFF_CNT  (OFF_CE + 4)
#define OFF_DUMPS 65536
#define RESERVED  OFF_DUMPS
#define NBLK 1024

// ---------------- float4 helpers ----------------
__device__ __forceinline__ float4 f4max(float4 a, float4 b) {
    return make_float4(fmaxf(a.x,b.x), fmaxf(a.y,b.y), fmaxf(a.z,b.z), fmaxf(a.w,b.w));
}
__device__ __forceinline__ float4 f4add(float4 a, float4 b) {
    return make_float4(a.x+b.x, a.y+b.y, a.z+b.z, a.w+b.w);
}
__device__ __forceinline__ float4 f4expsub(float4 a, float m) {
    return make_float4(__expf(a.x-m), __expf(a.y-m), __expf(a.z-m), __expf(a.w-m));
}
__device__ __forceinline__ u32 bin1(float e, float inv, int c, int t, float& pt) {
    float p = e * inv;
    if (c == t) pt = p;
    float err = (c == t) ? 1.0f - p : p;
    int b = (int)(err * 256.0f);
    return (u32)(b > 255 ? 255 : b);
}
__device__ __forceinline__ u32 pack4(float4 e, float inv, int cb, int t, float& pt) {
    return  bin1(e.x, inv, cb+0, t, pt)
         | (bin1(e.y, inv, cb+1, t, pt) << 8)
         | (bin1(e.z, inv, cb+2, t, pt) << 16)
         | (bin1(e.w, inv, cb+3, t, pt) << 24);
}

// full softmax + bin-pack; returns 5 packed words
__device__ __forceinline__ void compute_bins(
    const float* __restrict__ logits, int idx, int t,
    u32& w0, u32& w1, u32& w2, u32& w3, u32& w4, float& pt)
{
    const float4* row = (const float4*)(logits + (size_t)idx * NC);
    float4 v0 = row[0], v1 = row[1], v2 = row[2], v3 = row[3], v4 = row[4];
    float4 m4 = f4max(f4max(v0, v1), f4max(v2, v3));
    m4 = f4max(m4, v4);
    float mx = fmaxf(fmaxf(m4.x, m4.y), fmaxf(m4.z, m4.w));
    float4 e0 = f4expsub(v0, mx);
    float4 e1 = f4expsub(v1, mx);
    float4 e2 = f4expsub(v2, mx);
    float4 e3 = f4expsub(v3, mx);
    float4 e4 = f4expsub(v4, mx);
    float4 s4 = f4add(f4add(e0, e1), f4add(e2, e3));
    s4 = f4add(s4, e4);
    float s = (s4.x + s4.y) + (s4.z + s4.w);
    float inv = 1.0f / s;
    pt = 1.0f;
    w0 = pack4(e0, inv, 0,  t, pt);
    w1 = pack4(e1, inv, 4,  t, pt);
    w2 = pack4(e2, inv, 8,  t, pt);
    w3 = pack4(e3, inv, 12, t, pt);
    w4 = pack4(e4, inv, 16, t, pt);
}

// ---------------- store-pattern probes (half P; full compute feeds stores) ----------------
// MODE 1: 5-stream SoA dword stores (R4 pattern). MODE 2: byte-only store.
// MODE 3: aos16+w4s+t8 (production pattern). MODE 4: MODE 3 via nontemporal.
template<int MODE>
__global__ __launch_bounds__(BLK) void sprobe(
    const float* __restrict__ logits, const int* __restrict__ tgt, int P, int Peff,
    u32* __restrict__ aos16, u32* __restrict__ w4s, u8* __restrict__ t8,
    u32* __restrict__ soa)
{
    int tid = blockIdx.x * BLK + threadIdx.x;
    int stride = gridDim.x * BLK;
    for (int idx = tid; idx < Peff; idx += stride) {
        int t = tgt[idx];
        u32 w0, w1, w2, w3, w4; float pt;
        compute_bins(logits, idx, t, w0, w1, w2, w3, w4, pt);
        if constexpr (MODE == 1) {
            soa[idx]                 = w0;
            soa[(size_t)P + idx]     = w1;
            soa[(size_t)2 * P + idx] = w2;
            soa[(size_t)3 * P + idx] = w3;
            soa[(size_t)4 * P + idx] = w4;
        } else if constexpr (MODE == 2) {
            t8[idx] = (u8)(t + (w0 & 1));   // byte store only (w0 keeps compute live)
        } else if constexpr (MODE == 3) {
            v4i q = { (int)w0, (int)w1, (int)w2, (int)w3 };
            *(v4i*)(aos16 + (size_t)idx * 4) = q;
            w4s[idx] = w4;
            t8[idx] = (u8)t;
        } else {
            v4i q = { (int)w0, (int)w1, (int)w2, (int)w3 };
            __builtin_nontemporal_store(q, (v4i*)(aos16 + (size_t)idx * 4));
            __builtin_nontemporal_store(w4, &w4s[idx]);
            __builtin_nontemporal_store((u8)t, &t8[idx]);
        }
    }
}

// ---------------- k1a: streaming softmax + CE + AoS bin write ----------------
__global__ __launch_bounds__(BLK) void k1a_bins(
    const float* __restrict__ logits, const int* __restrict__ tgt, int P,
    u32* __restrict__ aos16, u32* __restrict__ w4s, u8* __restrict__ t8,
    float* __restrict__ ce_sum, u32* __restrict__ valid_cnt)
{
    int tid = blockIdx.x * BLK + threadIdx.x;
    int stride = gridDim.x * BLK;
    float ce_part = 0.f;
    u32   cnt_part = 0;

    for (int idx = tid; idx < P; idx += stride) {
        int t = tgt[idx];
        u32 w0, w1, w2, w3, w4; float pt;
        compute_bins(logits, idx, t, w0, w1, w2, w3, w4, pt);
        v4i q = { (int)w0, (int)w1, (int)w2, (int)w3 };
        *(v4i*)(aos16 + (size_t)idx * 4) = q;
        w4s[idx] = w4;
        t8[idx]  = (u8)t;
        if (t != 0) { ce_part -= __logf(pt); cnt_part++; }
    }

    #pragma unroll
    for (int off = 32; off > 0; off >>= 1) {
        ce_part  += __shfl_down(ce_part, off);
        cnt_part += __shfl_down(cnt_part, off);
    }
    if ((threadIdx.x & 63) == 0) {
        atomicAdd(ce_sum, ce_part);
        atomicAdd(valid_cnt, cnt_part);
    }
}

// ---------------- k1b: histogram from packed bins ----------------
__global__ void k1b_hist(
    const u32* __restrict__ aos16, const u32* __restrict__ w4s, const u8* __restrict__ t8,
    int P, u32* __restrict__ dumps)
{
    __shared__ u32 h[NCTR];
    for (int i = threadIdx.x; i < NCTR; i += BLK) h[i] = 0;
    __syncthreads();

    int tid = blockIdx.x * BLK + threadIdx.x;
    for (int idx = tid; idx < P; idx += NBLK * BLK) {
        int4 q = *(const int4*)(aos16 + (size_t)idx * 4);
        u32 w4 = w4s[idx];
        int t = t8[idx];
        u32 w[5] = { (u32)q.x, (u32)q.y, (u32)q.z, (u32)q.w, w4 };
        #pragma unroll
        for (int j = 0; j < 5; ++j) {
            #pragma unroll
            for (int k = 0; k < 4; ++k) {
                int c = j * 4 + k;
                u32 b = (w[j] >> (8 * k)) & 255u;
                atomicAdd(&h[(u32)c * 256u + b], (c == t) ? 0x10001u : 1u);
            }
        }
    }

    __syncthreads();
    u32* d = dumps + (size_t)blockIdx.x * NCTR;
    for (int i = threadIdx.x; i < NCTR; i += BLK) d[i] = h[i];
}

// ---------------- k2a: reduce + unpack per-block dumps ----------------
__global__ __launch_bounds__(256) void k2a_reduce(
    const u32* __restrict__ dumps, u32* __restrict__ final_hist, int nblk, int chunk)
{
    int counter = (blockIdx.x % 20) * 256 + threadIdx.x;
    int part    = blockIdx.x / 20;
    int b0 = part * chunk;
    int b1 = b0 + chunk; if (b1 > nblk) b1 = nblk;
    u32 lo = 0, hi = 0;
    for (int blk = b0; blk < b1; ++blk) {
        u32 v = dumps[(size_t)blk * NCTR + counter];
        lo += v & 0xFFFFu;
        hi += v >> 16;
    }
    if (lo) atomicAdd(&final_hist[counter], lo);
    if (hi) atomicAdd(&final_hist[NCTR + counter], hi);
}

// ---------------- k2b: per-class descending bin scan + finalize ----------------
__device__ __forceinline__ float jac_of(float gts, u32 cf, u32 ct)
{
    float I = gts - (float)cf;
    float U = gts + (float)ct - (float)cf;
    return 1.0f - I / U;
}

__global__ __launch_bounds__(256) void k2b_final(
    const u32* __restrict__ final_hist, const float* __restrict__ ce_sum,
    const u32* __restrict__ valid_cnt, float* __restrict__ outp)
{
    __shared__ u64 sc[NB];
    __shared__ float red[NB];
    int t = threadIdx.x;

    float lovsum = 0.f;
    int prescnt = 0;

    for (int c = 0; c < NC; ++c) {
        int b = NB - 1 - t;
        u32 tot = final_hist[c * NB + b];
        u32 fg  = final_hist[NCTR + c * NB + b];
        u64 v = ((u64)fg << 32) | (u64)tot;

        sc[t] = v;
        __syncthreads();
        for (int off = 1; off < NB; off <<= 1) {
            u64 add = (t >= off) ? sc[t - off] : 0ull;
            __syncthreads();
            sc[t] += add;
            __syncthreads();
        }
        u64 incl  = sc[t];
        u64 total = sc[NB - 1];
        float gts = (float)(u32)(total >> 32);

        float contrib = 0.f;
        if (gts > 0.f) {
            u64 excl = incl - v;
            float jE = jac_of(gts, (u32)(excl >> 32), (u32)excl);
            float jI = jac_of(gts, (u32)(incl >> 32), (u32)incl);
            float eb = ((float)b + 0.5f) * (1.0f / (float)NB);
            contrib = eb * (jI - jE);
        }

        red[t] = contrib;
        __syncthreads();
        #pragma unroll
        for (int off = NB / 2; off > 0; off >>= 1) {
            if (t < off) red[t] += red[t + off];
            __syncthreads();
        }
        if (t == 0 && gts > 0.f) { lovsum += red[0]; prescnt++; }
        __syncthreads();
    }

    if (t == 0) {
        u32 vc = *valid_cnt; if (vc < 1u) vc = 1u;
        float ce = *ce_sum / (float)vc;
        int pc = prescnt < 1 ? 1 : prescnt;
        float lov = lovsum / (float)pc;
        outp[0] = 2.0f * ce;
        outp[1] = 6.0f * lov;
    }
}

// ---------------- launch ----------------
extern "C" void kernel_launch(void* const* d_in, const int* in_sizes, int n_in,
                              void* d_out, int out_size, void* d_ws, size_t ws_size,
                              hipStream_t stream)
{
    const float* logits = (const float*)d_in[0];
    const int*   tgt    = (const int*)d_in[1];
    int P = in_sizes[1];

    char* ws = (char*)d_ws;
    u32*  final_hist = (u32*)ws;
    float* ce_sum    = (float*)(ws + OFF_CE);
    u32*  valid_cnt  = (u32*)(ws + OFF_CNT);
    u32*  dumps      = (u32*)(ws + OFF_DUMPS);

    size_t off_aos = (size_t)OFF_DUMPS + (size_t)NBLK * DUMP_BYTES;   // 21.04 MB
    u32* aos16 = (u32*)(ws + off_aos);                                 // 16 B/pt
    u32* w4s   = (u32*)(ws + off_aos + (size_t)16 * P);                // 4 B/pt
    u8*  t8    = (u8*) (ws + off_aos + (size_t)20 * P);                // 1 B/pt
    u32* soa   = (u32*)(ws + off_aos);                                 // probe-1 region (overwritten by k1a)

    int Peff = P >> 1;

    // ---- store-pattern ablation probes ----
    hipLaunchKernelGGL((sprobe<1>), dim3(NBLK), dim3(BLK), 0, stream, logits, tgt, P, Peff, aos16, w4s, t8, soa);
    hipLaunchKernelGGL((sprobe<2>), dim3(NBLK), dim3(BLK), 0, stream, logits, tgt, P, Peff, aos16, w4s, t8, soa);
    hipLaunchKernelGGL((sprobe<3>), dim3(NBLK), dim3(BLK), 0, stream, logits, tgt, P, Peff, aos16, w4s, t8, soa);
    hipLaunchKernelGGL((sprobe<4>), dim3(NBLK), dim3(BLK), 0, stream, logits, tgt, P, Peff, aos16, w4s, t8, soa);

    // ---- real pipeline ----
    hipMemsetAsync(d_ws, 0, RESERVED, stream);
    hipLaunchKernelGGL(k1a_bins, dim3(NBLK), dim3(BLK), 0, stream,
                       logits, tgt, P, aos16, w4s, t8, ce_sum, valid_cnt);
    hipLaunchKernelGGL(k1b_hist, dim3(NBLK), dim3(BLK), 0, stream,
                       aos16, w4s, t8, P, dumps);
    int split = 32;
    int chunk = (NBLK + split - 1) / split;
    hipLaunchKernelGGL(k2a_reduce, dim3(20 * split), dim3(256), 0, stream,
                       dumps, final_hist, NBLK, chunk);
    hipLaunchKernelGGL(k2b_final, dim3(1), dim3(NB), 0, stream,
                       final_hist, ce_sum, valid_cnt, (float*)d_out);
}